// Round 2
// baseline (147.204 us; speedup 1.0000x reference)
//
#include <hip/hip_runtime.h>

// Problem constants (from reference setup_inputs)
constexpr int B = 128;
constexpr int A = 1024;
constexpr int M = 6;
constexpr int T = 16;
constexpr int GRID = B * 4;     // 4 blocks per batch

constexpr float AGENT_THRESH = 0.5f;
constexpr float X_DIS_THRESH = 1.5f;
constexpr float Y_DIS_THRESH = 3.0f;
constexpr float DIS_THRESH_SQ = 9.0f;   // dist > 3.0  <=>  dist^2 > 9.0 (dist >= 0)
constexpr float PEN = 100.0f;

// Cross-block arrival counter. Zero-initialized at module load; the finishing
// block resets it to 0 each launch, so repeated graph replays stay correct.
__device__ int g_cnt = 0;

// Fused kernel: 4 blocks per batch, 256 threads/block, 1 agent per thread.
// Each block writes per-block partial mins ws[blockIdx][32] (slot = t*2 + xy),
// then the LAST block to arrive (device-scope atomic ticket) performs the
// final min-over-blocks + hinge loss + masked mean and writes out[0].
__global__ __launch_bounds__(256) void ppcl_fused(
    const float* __restrict__ ego,     // [B, T, 2]
    const float* __restrict__ fut,     // [B, A, M, T, 2]
    const float* __restrict__ score,   // [B, A, M]
    const float* __restrict__ mask,    // [B, T]
    float* __restrict__ ws,            // [GRID, 32]
    float* __restrict__ out)           // [1]
{
    const int b     = blockIdx.x >> 2;
    const int agent = ((blockIdx.x & 3) << 8) + threadIdx.x;

    // ego for this batch: uniform (blockIdx-derived) address on a const
    // __restrict__ pointer -> scalarizable; avoids LDS round-trip.
    float eg[T * 2];
    {
        const float4* ep = reinterpret_cast<const float4*>(ego + b * (T * 2));
#pragma unroll
        for (int i = 0; i < 8; ++i) {
            float4 q = ep[i];
            eg[4 * i + 0] = q.x;
            eg[4 * i + 1] = q.y;
            eg[4 * i + 2] = q.z;
            eg[4 * i + 3] = q.w;
        }
    }

    // argmax over the 6 mode scores (first-max semantics via strict >)
    // 24 B per agent, 8-byte aligned -> 3x float2
    const float2* sp2 = reinterpret_cast<const float2*>(
        score + ((size_t)b * A + agent) * M);
    float2 s01 = sp2[0], s23 = sp2[1], s45 = sp2[2];
    float best = s01.x;
    int   bm   = 0;
    if (s01.y > best) { best = s01.y; bm = 1; }
    if (s23.x > best) { best = s23.x; bm = 2; }
    if (s23.y > best) { best = s23.y; bm = 3; }
    if (s45.x > best) { best = s45.x; bm = 4; }
    if (s45.y > best) { best = s45.y; bm = 5; }
    const bool lowconf = (best < AGENT_THRESH);

    // best-mode trajectory: 32 contiguous floats, 128B-aligned -> 8x float4
    const float4* tp = reinterpret_cast<const float4*>(
        fut + (((size_t)b * A + agent) * M + bm) * (T * 2));

    float v[T * 2];   // v[2*t] = x_dist, v[2*t+1] = y_dist
#pragma unroll
    for (int i = 0; i < 8; ++i) {
        float4 q = tp[i];
        {
            const int t = 2 * i;
            float dx = eg[2 * t]     - q.x;
            float dy = eg[2 * t + 1] - q.y;
            float d2 = dx * dx + dy * dy;
            float pen = (d2 > DIS_THRESH_SQ || lowconf) ? PEN : 0.0f;
            v[2 * t]     = fabsf(dx) + pen;
            v[2 * t + 1] = fabsf(dy) + pen;
        }
        {
            const int t = 2 * i + 1;
            float dx = eg[2 * t]     - q.z;
            float dy = eg[2 * t + 1] - q.w;
            float d2 = dx * dx + dy * dy;
            float pen = (d2 > DIS_THRESH_SQ || lowconf) ? PEN : 0.0f;
            v[2 * t]     = fabsf(dx) + pen;
            v[2 * t + 1] = fabsf(dy) + pen;
        }
    }

    const int lane = threadIdx.x & 63;

    // Reduce-scatter butterfly over the 64-lane wave: each exchange halves the
    // live slot count (32->16->8->4->2->1); 32 shuffles total per thread.
#define RS_STEP(o, n)                                              \
    {                                                              \
        const bool hi = (lane & (o)) != 0;                         \
        _Pragma("unroll")                                          \
        for (int i = 0; i < (n); ++i) {                            \
            float send = hi ? v[i] : v[(n) + i];                   \
            float recv = __shfl_xor(send, (o), 64);                \
            float keep = hi ? v[(n) + i] : v[i];                   \
            v[i] = fminf(keep, recv);                              \
        }                                                          \
    }
    RS_STEP(32, 16)
    RS_STEP(16, 8)
    RS_STEP(8, 4)
    RS_STEP(4, 2)
    RS_STEP(2, 1)
#undef RS_STEP
    // lanes 2k and 2k+1 now hold the two halves of slot (lane>>1)&31
    v[0] = fminf(v[0], __shfl_xor(v[0], 1, 64));
    const int slot = (lane >> 1) & 31;

    // cross-wave reduction via 512 B of LDS
    __shared__ float s_red[4][T * 2];
    const int wave = threadIdx.x >> 6;
    if ((lane & 1) == 0) s_red[wave][slot] = v[0];
    __syncthreads();

    if (threadIdx.x < T * 2) {
        float m = fminf(fminf(s_red[0][threadIdx.x], s_red[1][threadIdx.x]),
                        fminf(s_red[2][threadIdx.x], s_red[3][threadIdx.x]));
        ws[(size_t)blockIdx.x * (T * 2) + threadIdx.x] = m;
    }

    // ---- arrival: last block performs the final reduction ----
    __shared__ int s_last;
    // __syncthreads() drains vmcnt(0) before s_barrier, so this block's ws
    // stores have left the CU (in L2) before we announce arrival.
    __syncthreads();
    if (threadIdx.x == 0) {
        // ACQ_REL + agent scope: release flushes this XCD's L2 (our ws lines),
        // acquire invalidates stale lines for the reads below. Device-scope
        // atomic is the coherence point across non-coherent per-XCD L2s.
        int prev = __hip_atomic_fetch_add(&g_cnt, 1, __ATOMIC_ACQ_REL,
                                          __HIP_MEMORY_SCOPE_AGENT);
        s_last = (prev == GRID - 1) ? 1 : 0;
    }
    __syncthreads();
    if (s_last == 0) return;

    // ---- finisher (former k2): min over 4 partial blocks per batch,
    //      hinge loss, mask, mean -> scalar ----
    float acc = 0.0f;
#pragma unroll
    for (int i = 0; i < 16; ++i) {
        const int vv  = i * 256 + threadIdx.x;   // 0..4095 = (b, t, xy)
        const int bb  = vv >> 5;
        const int rem = vv & 31;
        const int t   = rem >> 1;
        const int xy  = rem & 1;

        float m = ws[(size_t)(bb * 4 + 0) * 32 + rem];
        m = fminf(m, ws[(size_t)(bb * 4 + 1) * 32 + rem]);
        m = fminf(m, ws[(size_t)(bb * 4 + 2) * 32 + rem]);
        m = fminf(m, ws[(size_t)(bb * 4 + 3) * 32 + rem]);

        const float thr  = xy ? Y_DIS_THRESH : X_DIS_THRESH;
        float loss = (m <= thr) ? (thr - m) : 0.0f;
        loss *= mask[bb * T + t];
        acc += loss;
    }

    // 64-lane sum reduce
#pragma unroll
    for (int off = 32; off > 0; off >>= 1) acc += __shfl_xor(acc, off, 64);

    __shared__ float s_sum[4];
    if (lane == 0) s_sum[wave] = acc;
    __syncthreads();
    if (threadIdx.x == 0) {
        out[0] = (s_sum[0] + s_sum[1] + s_sum[2] + s_sum[3]) * (1.0f / (B * T * 2));
        // reset the arrival counter for the next launch (no concurrent access:
        // all GRID adds have completed by construction).
        __hip_atomic_store(&g_cnt, 0, __ATOMIC_RELAXED, __HIP_MEMORY_SCOPE_AGENT);
    }
}

extern "C" void kernel_launch(void* const* d_in, const int* in_sizes, int n_in,
                              void* d_out, int out_size, void* d_ws, size_t ws_size,
                              hipStream_t stream) {
    const float* ego   = (const float*)d_in[0];  // [B, T, 2]
    const float* fut   = (const float*)d_in[1];  // [B, A, M, T, 2]
    const float* score = (const float*)d_in[2];  // [B, A, M]
    const float* mask  = (const float*)d_in[3];  // [B, T]
    float* out = (float*)d_out;
    float* ws  = (float*)d_ws;                   // needs 512*32*4 = 64 KB

    ppcl_fused<<<GRID, 256, 0, stream>>>(ego, fut, score, mask, ws, out);
}

// Round 3
// 139.485 us; speedup vs baseline: 1.0553x; 1.0553x over previous
//
#include <hip/hip_runtime.h>

// Problem constants (from reference setup_inputs)
constexpr int B = 128;
constexpr int A = 1024;
constexpr int M = 6;
constexpr int T = 16;

constexpr float AGENT_THRESH = 0.5f;
constexpr float X_DIS_THRESH = 1.5f;
constexpr float Y_DIS_THRESH = 3.0f;
constexpr float DIS_THRESH_SQ = 9.0f;   // dist > 3.0  <=>  dist^2 > 9.0 (dist >= 0)
constexpr float PEN = 100.0f;

// k1: 4 blocks per batch, 256 threads/block, 1 agent per thread.
// Writes per-block partial mins ws[blockIdx][32] where slot = t*2 + (0=x,1=y).
//
// Reduction strategy: reduce-scatter butterfly. Each exchange step halves the
// number of live slots per lane (32->16->8->4->2->1), so total shuffles per
// thread are 16+8+4+2+1+1 = 32 instead of 6*32 = 192 for a full butterfly.
__global__ __launch_bounds__(256) void ppcl_k1(
    const float* __restrict__ ego,     // [B, T, 2]
    const float* __restrict__ fut,     // [B, A, M, T, 2]
    const float* __restrict__ score,   // [B, A, M]
    float* __restrict__ ws)            // [gridDim.x, 32]
{
    const int b     = blockIdx.x >> 2;
    const int agent = ((blockIdx.x & 3) << 8) + threadIdx.x;

    // ego for this batch: uniform (blockIdx-derived) address on a const
    // __restrict__ pointer -> scalarizable; avoids LDS round-trip.
    float eg[T * 2];
    {
        const float4* ep = reinterpret_cast<const float4*>(ego + b * (T * 2));
#pragma unroll
        for (int i = 0; i < 8; ++i) {
            float4 q = ep[i];
            eg[4 * i + 0] = q.x;
            eg[4 * i + 1] = q.y;
            eg[4 * i + 2] = q.z;
            eg[4 * i + 3] = q.w;
        }
    }

    // argmax over the 6 mode scores (first-max semantics via strict >)
    // 24 B per agent, 8-byte aligned -> 3x float2
    const float2* sp2 = reinterpret_cast<const float2*>(
        score + ((size_t)b * A + agent) * M);
    float2 s01 = sp2[0], s23 = sp2[1], s45 = sp2[2];
    float best = s01.x;
    int   bm   = 0;
    if (s01.y > best) { best = s01.y; bm = 1; }
    if (s23.x > best) { best = s23.x; bm = 2; }
    if (s23.y > best) { best = s23.y; bm = 3; }
    if (s45.x > best) { best = s45.x; bm = 4; }
    if (s45.y > best) { best = s45.y; bm = 5; }
    const bool lowconf = (best < AGENT_THRESH);

    // best-mode trajectory: 32 contiguous floats, 128B-aligned -> 8x float4
    const float4* tp = reinterpret_cast<const float4*>(
        fut + (((size_t)b * A + agent) * M + bm) * (T * 2));

    float v[T * 2];   // v[2*t] = x_dist, v[2*t+1] = y_dist
#pragma unroll
    for (int i = 0; i < 8; ++i) {
        float4 q = tp[i];
        {
            const int t = 2 * i;
            float dx = eg[2 * t]     - q.x;
            float dy = eg[2 * t + 1] - q.y;
            float d2 = dx * dx + dy * dy;
            float pen = (d2 > DIS_THRESH_SQ || lowconf) ? PEN : 0.0f;
            v[2 * t]     = fabsf(dx) + pen;
            v[2 * t + 1] = fabsf(dy) + pen;
        }
        {
            const int t = 2 * i + 1;
            float dx = eg[2 * t]     - q.z;
            float dy = eg[2 * t + 1] - q.w;
            float d2 = dx * dx + dy * dy;
            float pen = (d2 > DIS_THRESH_SQ || lowconf) ? PEN : 0.0f;
            v[2 * t]     = fabsf(dx) + pen;
            v[2 * t + 1] = fabsf(dy) + pen;
        }
    }

    const int lane = threadIdx.x & 63;

    // Reduce-scatter butterfly over the 64-lane wave.
#define RS_STEP(o, n)                                              \
    {                                                              \
        const bool hi = (lane & (o)) != 0;                         \
        _Pragma("unroll")                                          \
        for (int i = 0; i < (n); ++i) {                            \
            float send = hi ? v[i] : v[(n) + i];                   \
            float recv = __shfl_xor(send, (o), 64);                \
            float keep = hi ? v[(n) + i] : v[i];                   \
            v[i] = fminf(keep, recv);                              \
        }                                                          \
    }
    RS_STEP(32, 16)
    RS_STEP(16, 8)
    RS_STEP(8, 4)
    RS_STEP(4, 2)
    RS_STEP(2, 1)
#undef RS_STEP
    // lanes 2k and 2k+1 now hold the two halves of slot (lane>>1)&31
    v[0] = fminf(v[0], __shfl_xor(v[0], 1, 64));
    const int slot = (lane >> 1) & 31;

    // cross-wave reduction via 512 B of LDS
    __shared__ float s_red[4][T * 2];
    const int wave = threadIdx.x >> 6;
    if ((lane & 1) == 0) s_red[wave][slot] = v[0];
    __syncthreads();

    if (threadIdx.x < T * 2) {
        float m = fminf(fminf(s_red[0][threadIdx.x], s_red[1][threadIdx.x]),
                        fminf(s_red[2][threadIdx.x], s_red[3][threadIdx.x]));
        ws[(size_t)blockIdx.x * (T * 2) + threadIdx.x] = m;
    }
}

// k2: single 1024-thread block. Each thread owns one group of 4 consecutive
// slots of one batch: 4x dwordx4 loads (one per partial row), componentwise
// min, vectorized hinge, float2 mask. Then 16-wave sum reduce.
__global__ __launch_bounds__(1024) void ppcl_k2(
    const float* __restrict__ ws,     // [B*4, 32]
    const float* __restrict__ mask,   // [B, T]
    float* __restrict__ out)          // [1]
{
    const int G    = threadIdx.x;     // 0..1023 group id
    const int b    = G >> 3;          // 8 groups of 4 slots per batch
    const int grem = G & 7;           // slot base = grem*4

    const float4* w4 = reinterpret_cast<const float4*>(ws);
    // row stride in float4s = 32/4 = 8
    const int base = (b * 4) * 8 + grem;
    float4 m0 = w4[base + 0 * 8];
    float4 m1 = w4[base + 1 * 8];
    float4 m2 = w4[base + 2 * 8];
    float4 m3 = w4[base + 3 * 8];
    float4 m;
    m.x = fminf(fminf(m0.x, m1.x), fminf(m2.x, m3.x));
    m.y = fminf(fminf(m0.y, m1.y), fminf(m2.y, m3.y));
    m.z = fminf(fminf(m0.z, m1.z), fminf(m2.z, m3.z));
    m.w = fminf(fminf(m0.w, m1.w), fminf(m2.w, m3.w));

    // slots (4g, 4g+1, 4g+2, 4g+3) -> xy = (0,1,0,1), t = (2g', 2g', 2g'+1, 2g'+1)
    const float2 mk = *reinterpret_cast<const float2*>(mask + b * T + grem * 2);

    float acc = 0.0f;
    {
        float l = (m.x <= X_DIS_THRESH) ? (X_DIS_THRESH - m.x) : 0.0f;
        acc += l * mk.x;
    }
    {
        float l = (m.y <= Y_DIS_THRESH) ? (Y_DIS_THRESH - m.y) : 0.0f;
        acc += l * mk.x;
    }
    {
        float l = (m.z <= X_DIS_THRESH) ? (X_DIS_THRESH - m.z) : 0.0f;
        acc += l * mk.y;
    }
    {
        float l = (m.w <= Y_DIS_THRESH) ? (Y_DIS_THRESH - m.w) : 0.0f;
        acc += l * mk.y;
    }

    // 64-lane sum reduce, then 16 wave partials -> thread 0
#pragma unroll
    for (int off = 32; off > 0; off >>= 1) acc += __shfl_xor(acc, off, 64);

    __shared__ float s[16];
    const int wave = threadIdx.x >> 6;
    const int lane = threadIdx.x & 63;
    if (lane == 0) s[wave] = acc;
    __syncthreads();
    if (threadIdx.x == 0) {
        float t = 0.0f;
#pragma unroll
        for (int i = 0; i < 16; ++i) t += s[i];
        out[0] = t * (1.0f / (B * T * 2));
    }
}

extern "C" void kernel_launch(void* const* d_in, const int* in_sizes, int n_in,
                              void* d_out, int out_size, void* d_ws, size_t ws_size,
                              hipStream_t stream) {
    const float* ego   = (const float*)d_in[0];  // [B, T, 2]
    const float* fut   = (const float*)d_in[1];  // [B, A, M, T, 2]
    const float* score = (const float*)d_in[2];  // [B, A, M]
    const float* mask  = (const float*)d_in[3];  // [B, T]
    float* out = (float*)d_out;
    float* ws  = (float*)d_ws;                   // needs 512*32*4 = 64 KB

    ppcl_k1<<<B * 4, 256, 0, stream>>>(ego, fut, score, ws);
    ppcl_k2<<<1, 1024, 0, stream>>>(ws, mask, out);
}